// Round 22
// baseline (455.715 us; speedup 1.0000x reference)
//
#include <hip/hip_runtime.h>

#define SEQ   4096
#define NH    16
#define HD    80
#define DIM   1280
#define N3    3840
#define KDIM  1280
#define SCALE2 0.16129030407342303f  // 80^-0.5 * log2(e)  (q pre-scale; softmax in base-2)

typedef __bf16 bf16x8 __attribute__((ext_vector_type(8)));
typedef float  f32x4  __attribute__((ext_vector_type(4)));

#define MFMA16(A,B,C) __builtin_amdgcn_mfma_f32_16x16x32_bf16(A,B,C,0,0,0)
#define EXP2F(x) __builtin_amdgcn_exp2f(x)   // v_exp_f32: D = 2^S0

static __device__ __forceinline__ unsigned short f2bf(float x){
    unsigned int u = __builtin_bit_cast(unsigned int, x);
    u = (u + 0x7FFFu + ((u >> 16) & 1u)) >> 16;   // RTNE, finite inputs
    return (unsigned short)u;
}
static __device__ __forceinline__ float bf2f(unsigned short h){
    return __builtin_bit_cast(float, ((unsigned int)h) << 16);
}
static __device__ __forceinline__ int packp(float a, float b){
    return (int)f2bf(a) | ((int)f2bf(b) << 16);
}

// ---------------------------------------------------------------------------
// fp32 -> bf16 convert (hidden, qkv_w, proj_w)
// ---------------------------------------------------------------------------
__global__ __launch_bounds__(256)
void conv_kernel(const float* __restrict__ src, unsigned short* __restrict__ hi, int n4)
{
    for (int i = blockIdx.x * 256 + threadIdx.x; i < n4; i += gridDim.x * 256) {
        float4 x = ((const float4*)src)[i];
        uint2 hw;
        hw.x = (unsigned)f2bf(x.x) | ((unsigned)f2bf(x.y) << 16);
        hw.y = (unsigned)f2bf(x.z) | ((unsigned)f2bf(x.w) << 16);
        ((uint2*)hi)[i] = hw;
    }
}

// ---------------------------------------------------------------------------
// 256x256 tile 1-TERM bf16 MFMA GEMM (QKV; R21-proven, 2 blocks/CU).
// 512 thr, 8 waves 2x4, BK=64, full unroll, XCD swizzle.
// ---------------------------------------------------------------------------
template <bool SCATTER>
__global__ __launch_bounds__(512, 2)
void gemm256(const unsigned short* __restrict__ Ahi,
             const unsigned short* __restrict__ Bhi,
             const float* __restrict__ bias, float* __restrict__ C)
{
    __shared__ unsigned short sAh[256][72];
    __shared__ unsigned short sBh[256][72];

    const int tid = threadIdx.x;
    const int lane = tid & 63;
    const int lq = lane & 15;
    const int g = lane >> 4;
    const int wave = tid >> 6;
    const int wr = wave >> 2;
    const int wc = wave & 3;

    const int flat = blockIdx.x;
    const int xcd = flat & 7;
    const int j = flat >> 3;
    const int bm = (xcd * 2 + (j & 1)) * 256;
    const int bn = (j >> 1) * 256;

    int orow[4], ooc[4];
#pragma unroll
    for (int i = 0; i < 4; ++i) {
        const int o = tid + 512 * i;
        orow[i] = o >> 3;
        ooc[i] = (o & 7) * 8;
    }

    f32x4 acc[8][4];
#pragma unroll
    for (int i = 0; i < 8; ++i)
#pragma unroll
        for (int jj = 0; jj < 4; ++jj) acc[i][jj] = (f32x4)0.f;

    uint4 rA[4], rB[4];
#define LOAD_A(kb)                                                             \
    do {                                                                       \
        _Pragma("unroll")                                                      \
        for (int i = 0; i < 4; ++i) {                                          \
            const size_t ao = (size_t)(bm + orow[i]) * KDIM + (kb) + ooc[i];   \
            rA[i] = *(const uint4*)&Ahi[ao];                                   \
        }                                                                      \
    } while (0)
#define LOAD_B(kb)                                                             \
    do {                                                                       \
        _Pragma("unroll")                                                      \
        for (int i = 0; i < 4; ++i) {                                          \
            const size_t bo = (size_t)(bn + orow[i]) * KDIM + (kb) + ooc[i];   \
            rB[i] = *(const uint4*)&Bhi[bo];                                   \
        }                                                                      \
    } while (0)

#define COMPUTE_HALF(ks, MF0)                                                  \
    do {                                                                       \
        _Pragma("unroll")                                                      \
        for (int mf0 = 0; mf0 < 4; ++mf0) {                                    \
            const int mf = mf0 + (MF0);                                        \
            bf16x8 aH = *(const bf16x8*)&sAh[wr * 128 + mf * 16 + lq][(ks) * 32 + g * 8]; \
            _Pragma("unroll")                                                  \
            for (int nf = 0; nf < 4; ++nf)                                     \
                acc[mf][nf] = MFMA16(aH, bH[nf], acc[mf][nf]);                 \
        }                                                                      \
    } while (0)

    LOAD_A(0); LOAD_B(0);

    for (int kb = 0; kb < KDIM; kb += 64) {
        __syncthreads();
#pragma unroll
        for (int i = 0; i < 4; ++i) {
            *(uint4*)&sAh[orow[i]][ooc[i]] = rA[i];
            *(uint4*)&sBh[orow[i]][ooc[i]] = rB[i];
        }
        __syncthreads();
        const bool more = (kb + 64 < KDIM);

        {
            bf16x8 bH[4];
#pragma unroll
            for (int nf = 0; nf < 4; ++nf)
                bH[nf] = *(const bf16x8*)&sBh[wc * 64 + nf * 16 + lq][g * 8];
            COMPUTE_HALF(0, 0);
            COMPUTE_HALF(0, 4);
        }
        if (more) LOAD_A(kb + 64);
        {
            bf16x8 bH[4];
#pragma unroll
            for (int nf = 0; nf < 4; ++nf)
                bH[nf] = *(const bf16x8*)&sBh[wc * 64 + nf * 16 + lq][32 + g * 8];
            COMPUTE_HALF(1, 0);
            if (more) LOAD_B(kb + 64);
            COMPUTE_HALF(1, 4);
        }
    }
#undef LOAD_A
#undef LOAD_B
#undef COMPUTE_HALF

#pragma unroll
    for (int mf = 0; mf < 8; ++mf) {
        const int m = bm + wr * 128 + mf * 16 + g * 4;
#pragma unroll
        for (int nf = 0; nf < 4; ++nf) {
            const int n = bn + wc * 64 + nf * 16 + lq;
            const float bv = bias[n];
#pragma unroll
            for (int r = 0; r < 4; ++r) {
                const float v = acc[mf][nf][r] + bv;
                if (SCATTER) {
                    const int which = n / DIM;
                    const int rem = n - which * DIM;
                    const int hh = rem / HD;
                    const int d = rem - hh * HD;
                    C[((size_t)(which * NH + hh) * SEQ + (m + r)) * HD + d] = v;
                } else {
                    C[(size_t)(m + r) * DIM + n] = v;
                }
            }
        }
    }
}

// ---------------------------------------------------------------------------
// 128x128 tile 1-TERM bf16 MFMA GEMM (proj; R14-proven)
// ---------------------------------------------------------------------------
__global__ __launch_bounds__(256, 2)
void gemm_proj(const unsigned short* __restrict__ Ahi,
               const unsigned short* __restrict__ Bhi,
               const float* __restrict__ bias, float* __restrict__ C)
{
    __shared__ unsigned short sAh[128][72];
    __shared__ unsigned short sBh[128][72];

    const int tid = threadIdx.x;
    const int lane = tid & 63;
    const int lq = lane & 15;
    const int g = lane >> 4;
    const int wave = tid >> 6;
    const int wr = wave >> 1;
    const int wc = wave & 1;
    const int bm = blockIdx.y * 128;
    const int bn = blockIdx.x * 128;

    int orow[4], ooc[4];
#pragma unroll
    for (int i = 0; i < 4; ++i) {
        const int o = tid + 256 * i;
        orow[i] = o >> 3;
        ooc[i] = (o & 7) * 8;
    }

    f32x4 acc[4][4];
#pragma unroll
    for (int i = 0; i < 4; ++i)
#pragma unroll
        for (int j = 0; j < 4; ++j) acc[i][j] = (f32x4)0.f;

    uint4 rAh[4], rBh[4];
#define LOADT(kb)                                                                  \
    do {                                                                           \
        _Pragma("unroll")                                                          \
        for (int i = 0; i < 4; ++i) {                                              \
            const size_t ao = (size_t)(bm + orow[i]) * KDIM + (kb) + ooc[i];       \
            const size_t bo = (size_t)(bn + orow[i]) * KDIM + (kb) + ooc[i];       \
            rAh[i] = *(const uint4*)&Ahi[ao];                                      \
            rBh[i] = *(const uint4*)&Bhi[bo];                                      \
        }                                                                          \
    } while (0)

    LOADT(0);
    for (int kb = 0; kb < KDIM; kb += 64) {
        __syncthreads();
#pragma unroll
        for (int i = 0; i < 4; ++i) {
            *(uint4*)&sAh[orow[i]][ooc[i]] = rAh[i];
            *(uint4*)&sBh[orow[i]][ooc[i]] = rBh[i];
        }
        __syncthreads();
        if (kb + 64 < KDIM) LOADT(kb + 64);

#pragma unroll
        for (int ks = 0; ks < 2; ++ks) {
            bf16x8 aH[4], bH[4];
#pragma unroll
            for (int mf = 0; mf < 4; ++mf)
                aH[mf] = *(const bf16x8*)&sAh[wr * 64 + mf * 16 + lq][ks * 32 + g * 8];
#pragma unroll
            for (int nf = 0; nf < 4; ++nf)
                bH[nf] = *(const bf16x8*)&sBh[wc * 64 + nf * 16 + lq][ks * 32 + g * 8];
#pragma unroll
            for (int mf = 0; mf < 4; ++mf)
#pragma unroll
                for (int nf = 0; nf < 4; ++nf)
                    acc[mf][nf] = MFMA16(aH[mf], bH[nf], acc[mf][nf]);
        }
    }
#undef LOADT

#pragma unroll
    for (int mf = 0; mf < 4; ++mf) {
        const int m = bm + wr * 64 + mf * 16 + g * 4;
#pragma unroll
        for (int nf = 0; nf < 4; ++nf) {
            const int n = bn + wc * 64 + nf * 16 + lq;
            const float bv = bias[n];
#pragma unroll
            for (int r = 0; r < 4; ++r)
                C[(size_t)(m + r) * DIM + n] = acc[mf][nf][r] + bv;
        }
    }
}

// ---------------------------------------------------------------------------
// RoPE: q in-place (folds 80^-0.5*log2e); k -> khi bf16 plane.
// ---------------------------------------------------------------------------
__global__ __launch_bounds__(256)
void rope_split(float* __restrict__ q, const float* __restrict__ kin,
                unsigned short* __restrict__ khi,
                const float* __restrict__ cos_t, const float* __restrict__ sin_t)
{
    const int idx = blockIdx.x * 256 + threadIdx.x;   // over 2*NH*SEQ*40
    if (idx >= 2 * NH * SEQ * 40) return;
    const int d = idx % 40;
    const int s = (idx / 40) % SEQ;
    const int h = (idx / (40 * SEQ)) % NH;
    const int which = idx / (40 * SEQ * NH);
    const float c0 = cos_t[s * HD + d];
    const float c1 = cos_t[s * HD + d + 40];
    const float s0 = sin_t[s * HD + d];
    const float s1 = sin_t[s * HD + d + 40];
    const size_t base = ((size_t)h * SEQ + s) * HD;
    if (which == 0) {
        float* bp = q + base;
        const float x0 = bp[d];
        const float x1 = bp[d + 40];
        bp[d]      = (x0 * c0 - x1 * s0) * SCALE2;
        bp[d + 40] = (x1 * c1 + x0 * s1) * SCALE2;
    } else {
        const float* kp = kin + base;
        const float x0 = kp[d];
        const float x1 = kp[d + 40];
        khi[base + d]      = f2bf(x0 * c0 - x1 * s0);
        khi[base + d + 40] = f2bf(x1 * c1 + x0 * s1);
    }
}

// ---------------------------------------------------------------------------
// V transpose + bf16 convert: v[h][s][d] fp32 -> vt[h][d][s] bf16
// ---------------------------------------------------------------------------
__global__ __launch_bounds__(256)
void vtrans_kernel(const float* __restrict__ v, unsigned short* __restrict__ vt)
{
    __shared__ float tile[64][84];
    const int tid = threadIdx.x;
    const int h = blockIdx.y;
    const int s0 = blockIdx.x * 64;
    const float* vh = v + (size_t)h * SEQ * HD;
#pragma unroll
    for (int ii = 0; ii < 5; ++ii) {
        const int id = tid + 256 * ii;
        const int r = id / 20, c4 = (id % 20) * 4;
        *(float4*)&tile[r][c4] = *(const float4*)(vh + (size_t)(s0 + r) * HD + c4);
    }
    __syncthreads();
#pragma unroll
    for (int ii = 0; ii < 5; ++ii) {
        const int id = tid + 256 * ii;
        const int d = id >> 4, c = (id & 15) * 4;
        const unsigned int u0 = f2bf(tile[c + 0][d]);
        const unsigned int u1 = f2bf(tile[c + 1][d]);
        const unsigned int u2 = f2bf(tile[c + 2][d]);
        const unsigned int u3 = f2bf(tile[c + 3][d]);
        uint2 w; w.x = u0 | (u1 << 16); w.y = u2 | (u3 << 16);
        *(uint2*)(vt + ((size_t)h * HD + d) * SEQ + s0 + c) = w;
    }
}

// ---------------------------------------------------------------------------
// MFMA flash attention v10: R20 kernel + DOUBLE-BUFFERED K/V LDS with ONE
// barrier per tile (was two). Safety: the write to buf[(t+1)&1] at iter t
// races only with reads of that buffer at iter t-1; every wave passes the
// top-of-t barrier only after finishing t-1's compute, so a single barrier
// per iteration suffices. Stage writes now overlap other waves' compute
// (T14 write-late); barrier count 128 -> 65. Math bit-identical to R20.
// LDS 25 -> 49.6 KB (still >=3 blocks/CU by LDS; reg-capped at 2 waves/SIMD
// as before -- the gain is serialization removal, not occupancy).
// ---------------------------------------------------------------------------
__global__ __launch_bounds__(256, 2)
void attn_mfma(const float* __restrict__ q, const unsigned short* __restrict__ khi,
               const unsigned short* __restrict__ vt,
               unsigned short* __restrict__ oHi)
{
    __shared__ unsigned short Khi[2][64][104];
    __shared__ unsigned short Vt[2][80][72];

    const int tid = threadIdx.x;
    const int wq = tid >> 6;
    const int lane = tid & 63;
    const int lq = lane & 15;
    const int g = lane >> 4;
    const int h = blockIdx.y;
    const int qb = blockIdx.x * 128;

    const float* qh = q + (size_t)h * SEQ * HD;
    const unsigned short* khi_h = khi + (size_t)h * SEQ * HD;
    const unsigned short* vth = vt + (size_t)h * HD * SEQ;

    // zero K pad columns [80,104) once (both buffers)
    for (int i = tid; i < 64 * 24; i += 256) {
        const int r = i / 24, c = 80 + i % 24;
        Khi[0][r][c] = 0; Khi[1][r][c] = 0;
    }

    int kr_[5], kc_[5], vd_[5], vc_[5];
#pragma unroll
    for (int ii = 0; ii < 5; ++ii) {
        const int id = tid + 256 * ii;
        kr_[ii] = id / 20; kc_[ii] = (id % 20) * 4;
        vd_[ii] = id >> 4; vc_[ii] = (id & 15) * 4;
    }

    bf16x8 qhiF[2][3], qloF[2][3];
#pragma unroll
    for (int nf = 0; nf < 2; ++nf) {
        const int qr = qb + wq * 32 + nf * 16 + lq;
        const float* qp = qh + (size_t)qr * HD;
#pragma unroll
        for (int ks = 0; ks < 3; ++ks) {
            const int d0 = ks * 32 + g * 8;
            union { unsigned short u[8]; bf16x8 v; } uh, ul;
            if (d0 < 80) {
                float4 x0 = *(const float4*)(qp + d0);
                float4 x1 = *(const float4*)(qp + d0 + 4);
                float xs[8] = {x0.x, x0.y, x0.z, x0.w, x1.x, x1.y, x1.z, x1.w};
#pragma unroll
                for (int i = 0; i < 8; ++i) {
                    const unsigned short hb = f2bf(xs[i]);
                    uh.u[i] = hb;
                    ul.u[i] = f2bf(xs[i] - bf2f(hb));
                }
            } else {
#pragma unroll
                for (int i = 0; i < 8; ++i) { uh.u[i] = 0; ul.u[i] = 0; }
            }
            qhiF[nf][ks] = uh.v; qloF[nf][ks] = ul.v;
        }
    }

    f32x4 o[2][5];
#pragma unroll
    for (int a = 0; a < 2; ++a)
#pragma unroll
        for (int b = 0; b < 5; ++b) o[a][b] = (f32x4)0.f;
    float mrow[2] = {-1e30f, -1e30f};
    float lrow[2] = {0.f, 0.f};

    uint2 kh_[5], vv_[5];
#define LOADKV(kb_)                                                                   \
    do {                                                                              \
        _Pragma("unroll")                                                             \
        for (int ii = 0; ii < 5; ++ii) {                                              \
            kh_[ii] = *(const uint2*)&khi_h[(size_t)((kb_) + kr_[ii]) * HD + kc_[ii]];\
            vv_[ii] = *(const uint2*)&vth[(size_t)vd_[ii] * SEQ + (kb_) + vc_[ii]];   \
        }                                                                             \
    } while (0)
#define STOREKV(buf)                                                                  \
    do {                                                                              \
        _Pragma("unroll")                                                             \
        for (int ii = 0; ii < 5; ++ii) {                                              \
            *(uint2*)&Khi[buf][kr_[ii]][kc_[ii]] = kh_[ii];                           \
            *(uint2*)&Vt[buf][vd_[ii]][vc_[ii]] = vv_[ii];                            \
        }                                                                             \
    } while (0)

    // prologue: fetch tile 0 and write into buffer 0
    LOADKV(0);
    STOREKV(0);

    for (int kb = 0; kb < SEQ; kb += 64) {
        const int cur = (kb >> 6) & 1;
        __syncthreads();   // buf[cur] writes complete; prev iter's reads of buf[cur^1] done
        const bool more = (kb + 64 < SEQ);
        if (more) LOADKV(kb + 64);   // reg prefetch (latency hides under compute)

        // ---- QK^T (swapped): St[kv][q], 2-term hi/lo ----
        f32x4 s[4][2];
#pragma unroll
        for (int mf = 0; mf < 4; ++mf)
#pragma unroll
            for (int nf = 0; nf < 2; ++nf) s[mf][nf] = (f32x4)0.f;
        __builtin_amdgcn_s_setprio(1);
#pragma unroll
        for (int ks = 0; ks < 3; ++ks) {
#pragma unroll
            for (int mf = 0; mf < 4; ++mf) {
                bf16x8 ah = *(const bf16x8*)&Khi[cur][mf * 16 + lq][ks * 32 + g * 8];
#pragma unroll
                for (int nf = 0; nf < 2; ++nf) {
                    s[mf][nf] = MFMA16(ah, qhiF[nf][ks], s[mf][nf]);
                    s[mf][nf] = MFMA16(ah, qloF[nf][ks], s[mf][nf]);
                }
            }
        }
        __builtin_amdgcn_s_setprio(0);

        // ---- online softmax (base 2) with defer-max skip (bit-exact) ----
        float alpha_s[2]; bool skip_s[2];
#pragma unroll
        for (int nf = 0; nf < 2; ++nf) {
            float mx = s[0][nf][0];
#pragma unroll
            for (int mf = 0; mf < 4; ++mf)
#pragma unroll
                for (int r = 0; r < 4; ++r) mx = fmaxf(mx, s[mf][nf][r]);
            mx = fmaxf(mx, __shfl_xor(mx, 16));
            mx = fmaxf(mx, __shfl_xor(mx, 32));
            const bool skip = __all(mx <= mrow[nf]);
            const float mnew = skip ? mrow[nf] : fmaxf(mrow[nf], mx);
            float sum = 0.f;
#pragma unroll
            for (int mf = 0; mf < 4; ++mf)
#pragma unroll
                for (int r = 0; r < 4; ++r) {
                    const float p = EXP2F(s[mf][nf][r] - mnew);
                    s[mf][nf][r] = p;
                    sum += p;
                }
            sum += __shfl_xor(sum, 16);
            sum += __shfl_xor(sum, 32);
            if (skip) {
                lrow[nf] += sum;
                alpha_s[nf] = 1.f;
            } else {
                const float a = EXP2F(mrow[nf] - mnew);
                lrow[nf] = lrow[nf] * a + sum;
                mrow[nf] = mnew;
                alpha_s[nf] = a;
            }
            skip_s[nf] = skip;
        }

        // ---- rescale O (skipped when alpha==1 exactly) ----
#pragma unroll
        for (int qm = 0; qm < 2; ++qm) {
            if (!skip_s[qm]) {
#pragma unroll
                for (int r = 0; r < 4; ++r) {
                    const float ao = __shfl(alpha_s[qm], (g << 2) | r);
#pragma unroll
                    for (int dn = 0; dn < 5; ++dn) o[qm][dn][r] *= ao;
                }
            }
        }

        // ---- pack P to bf16 pairs ----
        int pk[4][2][2];
#pragma unroll
        for (int mf = 0; mf < 4; ++mf)
#pragma unroll
            for (int nf = 0; nf < 2; ++nf) {
                pk[mf][nf][0] = packp(s[mf][nf][0], s[mf][nf][1]);
                pk[mf][nf][1] = packp(s[mf][nf][2], s[mf][nf][3]);
            }

        // ---- redistribute P to PV A-fragments (8 shfl/frag) ----
        bf16x8 pfrag[2][2];
#pragma unroll
        for (int qm = 0; qm < 2; ++qm) {
#pragma unroll
            for (int ks2 = 0; ks2 < 2; ++ks2) {
                union { int w[4]; bf16x8 v; } pw;
#pragma unroll
                for (int j = 0; j < 4; ++j) {
                    const int srcLane = lq + 32 * ((lane >> 4) & 1) + 16 * (j >> 1);
                    const int vA = __shfl(pk[2 * ks2 + 0][qm][j & 1], srcLane);
                    const int vB = __shfl(pk[2 * ks2 + 1][qm][j & 1], srcLane);
                    pw.w[j] = (lane >> 5) ? vB : vA;
                }
                pfrag[qm][ks2] = pw.v;
            }
        }

        // ---- PV: O += P @ V ----
        __builtin_amdgcn_s_setprio(1);
#pragma unroll
        for (int ks2 = 0; ks2 < 2; ++ks2) {
#pragma unroll
            for (int dn = 0; dn < 5; ++dn) {
                bf16x8 vb = *(const bf16x8*)&Vt[cur][dn * 16 + lq][ks2 * 32 + g * 8];
#pragma unroll
                for (int qm = 0; qm < 2; ++qm)
                    o[qm][dn] = MFMA16(pfrag[qm][ks2], vb, o[qm][dn]);
            }
        }
        __builtin_amdgcn_s_setprio(0);

        // ---- write next tile into the other buffer (overlaps other waves'
        //      compute; next read protected by the top-of-loop barrier) ----
        if (more) STOREKV(cur ^ 1);
    }
#undef LOADKV
#undef STOREKV

#pragma unroll
    for (int qm = 0; qm < 2; ++qm) {
        const float invl = 1.0f / lrow[qm];
#pragma unroll
        for (int r = 0; r < 4; ++r) {
            const float iv = __shfl(invl, (g << 2) | r);
            const int row = qb + wq * 32 + qm * 16 + g * 4 + r;
#pragma unroll
            for (int dn = 0; dn < 5; ++dn) {
                const float val = o[qm][dn][r] * iv;
                oHi[(size_t)row * DIM + h * HD + dn * 16 + lq] = f2bf(val);
            }
        }
    }
}

// ---------------------------------------------------------------------------
extern "C" void kernel_launch(void* const* d_in, const int* in_sizes, int n_in,
                              void* d_out, int out_size, void* d_ws, size_t ws_size,
                              hipStream_t stream)
{
    const float* hidden = (const float*)d_in[0];
    const float* cos_t  = (const float*)d_in[2];
    const float* sin_t  = (const float*)d_in[3];
    const float* qkv_w  = (const float*)d_in[4];
    const float* qkv_b  = (const float*)d_in[5];
    const float* proj_w = (const float*)d_in[6];
    const float* proj_b = (const float*)d_in[7];
    float* out = (float*)d_out;

    char* ws = (char*)d_ws;
    // R21-proven region map:
    float* qkv = (float*)ws;                                   // q fp32 [0, 21.0M)
    float* qf  = qkv;
    float* kf  = qkv + (size_t)NH * SEQ * HD;                  // k fp32 [21.0M, 41.9M)
    float* vf  = qkv + (size_t)2 * NH * SEQ * HD;              // v fp32 [41.9M, 62.9M)
    unsigned short* aHi = (unsigned short*)(ws + 20971520);    // over k fp32 (dead after rope)
    unsigned short* pHi = (unsigned short*)(ws + 41943040);    // over v fp32 (dead after vtrans)
    unsigned short* hHi = (unsigned short*)(ws + 62914560);    // hidden bf16 (dead after QKV gemm)
    unsigned short* khi = (unsigned short*)(ws + 62914560);    // over hHi (after QKV gemm)
    unsigned short* wHi = (unsigned short*)(ws + 73400320);    // qkv_w bf16 (dead after QKV gemm)
    unsigned short* vth = (unsigned short*)(ws + 73400320);    // over wHi (after QKV gemm)

    conv_kernel<<<2048, 256, 0, stream>>>(hidden, hHi, SEQ * DIM / 4);
    conv_kernel<<<2048, 256, 0, stream>>>(qkv_w, wHi, N3 * DIM / 4);

    gemm256<true><<<dim3(16 * (N3 / 256)), 512, 0, stream>>>(
        hHi, wHi, qkv_b, qkv);

    rope_split<<<(2 * NH * SEQ * 40 + 255) / 256, 256, 0, stream>>>(
        qf, kf, khi, cos_t, sin_t);

    vtrans_kernel<<<dim3(SEQ / 64, NH), 256, 0, stream>>>(vf, vth);

    conv_kernel<<<1024, 256, 0, stream>>>(proj_w, pHi, DIM * DIM / 4);

    attn_mfma<<<dim3(SEQ / 128, NH), 256, 0, stream>>>(qf, khi, vth, aHi);

    gemm_proj<<<dim3(DIM / 128, SEQ / 128), 256, 0, stream>>>(
        aHi, pHi, proj_b, out);
}

// Round 23
// 444.942 us; speedup vs baseline: 1.0242x; 1.0242x over previous
//
#include <hip/hip_runtime.h>

#define SEQ   4096
#define NH    16
#define HD    80
#define DIM   1280
#define N3    3840
#define KDIM  1280
#define SCALE2 0.16129030407342303f  // 80^-0.5 * log2(e)  (q pre-scale; softmax in base-2)

typedef __bf16 bf16x8 __attribute__((ext_vector_type(8)));
typedef float  f32x4  __attribute__((ext_vector_type(4)));

#define MFMA16(A,B,C) __builtin_amdgcn_mfma_f32_16x16x32_bf16(A,B,C,0,0,0)
#define EXP2F(x) __builtin_amdgcn_exp2f(x)   // v_exp_f32: D = 2^S0

static __device__ __forceinline__ unsigned short f2bf(float x){
    unsigned int u = __builtin_bit_cast(unsigned int, x);
    u = (u + 0x7FFFu + ((u >> 16) & 1u)) >> 16;   // RTNE, finite inputs
    return (unsigned short)u;
}
static __device__ __forceinline__ float bf2f(unsigned short h){
    return __builtin_bit_cast(float, ((unsigned int)h) << 16);
}
static __device__ __forceinline__ int packp(float a, float b){
    return (int)f2bf(a) | ((int)f2bf(b) << 16);
}

// ---------------------------------------------------------------------------
// fp32 -> bf16 convert (hidden, qkv_w, proj_w)
// ---------------------------------------------------------------------------
__global__ __launch_bounds__(256)
void conv_kernel(const float* __restrict__ src, unsigned short* __restrict__ hi, int n4)
{
    for (int i = blockIdx.x * 256 + threadIdx.x; i < n4; i += gridDim.x * 256) {
        float4 x = ((const float4*)src)[i];
        uint2 hw;
        hw.x = (unsigned)f2bf(x.x) | ((unsigned)f2bf(x.y) << 16);
        hw.y = (unsigned)f2bf(x.z) | ((unsigned)f2bf(x.w) << 16);
        ((uint2*)hi)[i] = hw;
    }
}

// ---------------------------------------------------------------------------
// 256x256 tile 1-TERM bf16 MFMA GEMM (QKV; R21-proven, 2 blocks/CU).
// 512 thr, 8 waves 2x4, BK=64, full unroll, XCD swizzle.
// ---------------------------------------------------------------------------
template <bool SCATTER>
__global__ __launch_bounds__(512, 2)
void gemm256(const unsigned short* __restrict__ Ahi,
             const unsigned short* __restrict__ Bhi,
             const float* __restrict__ bias, float* __restrict__ C)
{
    __shared__ unsigned short sAh[256][72];
    __shared__ unsigned short sBh[256][72];

    const int tid = threadIdx.x;
    const int lane = tid & 63;
    const int lq = lane & 15;
    const int g = lane >> 4;
    const int wave = tid >> 6;
    const int wr = wave >> 2;
    const int wc = wave & 3;

    const int flat = blockIdx.x;
    const int xcd = flat & 7;
    const int j = flat >> 3;
    const int bm = (xcd * 2 + (j & 1)) * 256;
    const int bn = (j >> 1) * 256;

    int orow[4], ooc[4];
#pragma unroll
    for (int i = 0; i < 4; ++i) {
        const int o = tid + 512 * i;
        orow[i] = o >> 3;
        ooc[i] = (o & 7) * 8;
    }

    f32x4 acc[8][4];
#pragma unroll
    for (int i = 0; i < 8; ++i)
#pragma unroll
        for (int jj = 0; jj < 4; ++jj) acc[i][jj] = (f32x4)0.f;

    uint4 rA[4], rB[4];
#define LOAD_A(kb)                                                             \
    do {                                                                       \
        _Pragma("unroll")                                                      \
        for (int i = 0; i < 4; ++i) {                                          \
            const size_t ao = (size_t)(bm + orow[i]) * KDIM + (kb) + ooc[i];   \
            rA[i] = *(const uint4*)&Ahi[ao];                                   \
        }                                                                      \
    } while (0)
#define LOAD_B(kb)                                                             \
    do {                                                                       \
        _Pragma("unroll")                                                      \
        for (int i = 0; i < 4; ++i) {                                          \
            const size_t bo = (size_t)(bn + orow[i]) * KDIM + (kb) + ooc[i];   \
            rB[i] = *(const uint4*)&Bhi[bo];                                   \
        }                                                                      \
    } while (0)

#define COMPUTE_HALF(ks, MF0)                                                  \
    do {                                                                       \
        _Pragma("unroll")                                                      \
        for (int mf0 = 0; mf0 < 4; ++mf0) {                                    \
            const int mf = mf0 + (MF0);                                        \
            bf16x8 aH = *(const bf16x8*)&sAh[wr * 128 + mf * 16 + lq][(ks) * 32 + g * 8]; \
            _Pragma("unroll")                                                  \
            for (int nf = 0; nf < 4; ++nf)                                     \
                acc[mf][nf] = MFMA16(aH, bH[nf], acc[mf][nf]);                 \
        }                                                                      \
    } while (0)

    LOAD_A(0); LOAD_B(0);

    for (int kb = 0; kb < KDIM; kb += 64) {
        __syncthreads();
#pragma unroll
        for (int i = 0; i < 4; ++i) {
            *(uint4*)&sAh[orow[i]][ooc[i]] = rA[i];
            *(uint4*)&sBh[orow[i]][ooc[i]] = rB[i];
        }
        __syncthreads();
        const bool more = (kb + 64 < KDIM);

        {
            bf16x8 bH[4];
#pragma unroll
            for (int nf = 0; nf < 4; ++nf)
                bH[nf] = *(const bf16x8*)&sBh[wc * 64 + nf * 16 + lq][g * 8];
            COMPUTE_HALF(0, 0);
            COMPUTE_HALF(0, 4);
        }
        if (more) LOAD_A(kb + 64);
        {
            bf16x8 bH[4];
#pragma unroll
            for (int nf = 0; nf < 4; ++nf)
                bH[nf] = *(const bf16x8*)&sBh[wc * 64 + nf * 16 + lq][32 + g * 8];
            COMPUTE_HALF(1, 0);
            if (more) LOAD_B(kb + 64);
            COMPUTE_HALF(1, 4);
        }
    }
#undef LOAD_A
#undef LOAD_B
#undef COMPUTE_HALF

#pragma unroll
    for (int mf = 0; mf < 8; ++mf) {
        const int m = bm + wr * 128 + mf * 16 + g * 4;
#pragma unroll
        for (int nf = 0; nf < 4; ++nf) {
            const int n = bn + wc * 64 + nf * 16 + lq;
            const float bv = bias[n];
#pragma unroll
            for (int r = 0; r < 4; ++r) {
                const float v = acc[mf][nf][r] + bv;
                if (SCATTER) {
                    const int which = n / DIM;
                    const int rem = n - which * DIM;
                    const int hh = rem / HD;
                    const int d = rem - hh * HD;
                    C[((size_t)(which * NH + hh) * SEQ + (m + r)) * HD + d] = v;
                } else {
                    C[(size_t)(m + r) * DIM + n] = v;
                }
            }
        }
    }
}

// ---------------------------------------------------------------------------
// 128x128 tile 1-TERM bf16 MFMA GEMM (proj; R14-proven)
// ---------------------------------------------------------------------------
__global__ __launch_bounds__(256, 2)
void gemm_proj(const unsigned short* __restrict__ Ahi,
               const unsigned short* __restrict__ Bhi,
               const float* __restrict__ bias, float* __restrict__ C)
{
    __shared__ unsigned short sAh[128][72];
    __shared__ unsigned short sBh[128][72];

    const int tid = threadIdx.x;
    const int lane = tid & 63;
    const int lq = lane & 15;
    const int g = lane >> 4;
    const int wave = tid >> 6;
    const int wr = wave >> 1;
    const int wc = wave & 1;
    const int bm = blockIdx.y * 128;
    const int bn = blockIdx.x * 128;

    int orow[4], ooc[4];
#pragma unroll
    for (int i = 0; i < 4; ++i) {
        const int o = tid + 256 * i;
        orow[i] = o >> 3;
        ooc[i] = (o & 7) * 8;
    }

    f32x4 acc[4][4];
#pragma unroll
    for (int i = 0; i < 4; ++i)
#pragma unroll
        for (int j = 0; j < 4; ++j) acc[i][j] = (f32x4)0.f;

    uint4 rAh[4], rBh[4];
#define LOADT(kb)                                                                  \
    do {                                                                           \
        _Pragma("unroll")                                                          \
        for (int i = 0; i < 4; ++i) {                                              \
            const size_t ao = (size_t)(bm + orow[i]) * KDIM + (kb) + ooc[i];       \
            const size_t bo = (size_t)(bn + orow[i]) * KDIM + (kb) + ooc[i];       \
            rAh[i] = *(const uint4*)&Ahi[ao];                                      \
            rBh[i] = *(const uint4*)&Bhi[bo];                                      \
        }                                                                          \
    } while (0)

    LOADT(0);
    for (int kb = 0; kb < KDIM; kb += 64) {
        __syncthreads();
#pragma unroll
        for (int i = 0; i < 4; ++i) {
            *(uint4*)&sAh[orow[i]][ooc[i]] = rAh[i];
            *(uint4*)&sBh[orow[i]][ooc[i]] = rBh[i];
        }
        __syncthreads();
        if (kb + 64 < KDIM) LOADT(kb + 64);

#pragma unroll
        for (int ks = 0; ks < 2; ++ks) {
            bf16x8 aH[4], bH[4];
#pragma unroll
            for (int mf = 0; mf < 4; ++mf)
                aH[mf] = *(const bf16x8*)&sAh[wr * 64 + mf * 16 + lq][ks * 32 + g * 8];
#pragma unroll
            for (int nf = 0; nf < 4; ++nf)
                bH[nf] = *(const bf16x8*)&sBh[wc * 64 + nf * 16 + lq][ks * 32 + g * 8];
#pragma unroll
            for (int mf = 0; mf < 4; ++mf)
#pragma unroll
                for (int nf = 0; nf < 4; ++nf)
                    acc[mf][nf] = MFMA16(aH[mf], bH[nf], acc[mf][nf]);
        }
    }
#undef LOADT

#pragma unroll
    for (int mf = 0; mf < 4; ++mf) {
        const int m = bm + wr * 64 + mf * 16 + g * 4;
#pragma unroll
        for (int nf = 0; nf < 4; ++nf) {
            const int n = bn + wc * 64 + nf * 16 + lq;
            const float bv = bias[n];
#pragma unroll
            for (int r = 0; r < 4; ++r)
                C[(size_t)(m + r) * DIM + n] = acc[mf][nf][r] + bv;
        }
    }
}

// ---------------------------------------------------------------------------
// RoPE: q in-place (folds 80^-0.5*log2e); k -> khi bf16 plane.
// ---------------------------------------------------------------------------
__global__ __launch_bounds__(256)
void rope_split(float* __restrict__ q, const float* __restrict__ kin,
                unsigned short* __restrict__ khi,
                const float* __restrict__ cos_t, const float* __restrict__ sin_t)
{
    const int idx = blockIdx.x * 256 + threadIdx.x;   // over 2*NH*SEQ*40
    if (idx >= 2 * NH * SEQ * 40) return;
    const int d = idx % 40;
    const int s = (idx / 40) % SEQ;
    const int h = (idx / (40 * SEQ)) % NH;
    const int which = idx / (40 * SEQ * NH);
    const float c0 = cos_t[s * HD + d];
    const float c1 = cos_t[s * HD + d + 40];
    const float s0 = sin_t[s * HD + d];
    const float s1 = sin_t[s * HD + d + 40];
    const size_t base = ((size_t)h * SEQ + s) * HD;
    if (which == 0) {
        float* bp = q + base;
        const float x0 = bp[d];
        const float x1 = bp[d + 40];
        bp[d]      = (x0 * c0 - x1 * s0) * SCALE2;
        bp[d + 40] = (x1 * c1 + x0 * s1) * SCALE2;
    } else {
        const float* kp = kin + base;
        const float x0 = kp[d];
        const float x1 = kp[d + 40];
        khi[base + d]      = f2bf(x0 * c0 - x1 * s0);
        khi[base + d + 40] = f2bf(x1 * c1 + x0 * s1);
    }
}

// ---------------------------------------------------------------------------
// V transpose + bf16 convert: v[h][s][d] fp32 -> vt[h][d][s] bf16
// ---------------------------------------------------------------------------
__global__ __launch_bounds__(256)
void vtrans_kernel(const float* __restrict__ v, unsigned short* __restrict__ vt)
{
    __shared__ float tile[64][84];
    const int tid = threadIdx.x;
    const int h = blockIdx.y;
    const int s0 = blockIdx.x * 64;
    const float* vh = v + (size_t)h * SEQ * HD;
#pragma unroll
    for (int ii = 0; ii < 5; ++ii) {
        const int id = tid + 256 * ii;
        const int r = id / 20, c4 = (id % 20) * 4;
        *(float4*)&tile[r][c4] = *(const float4*)(vh + (size_t)(s0 + r) * HD + c4);
    }
    __syncthreads();
#pragma unroll
    for (int ii = 0; ii < 5; ++ii) {
        const int id = tid + 256 * ii;
        const int d = id >> 4, c = (id & 15) * 4;
        const unsigned int u0 = f2bf(tile[c + 0][d]);
        const unsigned int u1 = f2bf(tile[c + 1][d]);
        const unsigned int u2 = f2bf(tile[c + 2][d]);
        const unsigned int u3 = f2bf(tile[c + 3][d]);
        uint2 w; w.x = u0 | (u1 << 16); w.y = u2 | (u3 << 16);
        *(uint2*)(vt + ((size_t)h * HD + d) * SEQ + s0 + c) = w;
    }
}

// ---------------------------------------------------------------------------
// MFMA flash attention (R14/R20/R21-proven, 236 us): LDS-staged K/V, 2-term
// QK, defer-max (bit-exact), shfl P-redistribution, reg-prefetch, base-2
// softmax, setprio. 4 waves x 32 q-rows, grid (SEQ/128, NH).
// (R22's single-barrier double-buffer regressed: with 2 blocks/CU the
// two-barrier stall is already masked by the co-resident block, and the
// post-PV stage-write lengthened the critical path.)
// ---------------------------------------------------------------------------
__global__ __launch_bounds__(256, 2)
void attn_mfma(const float* __restrict__ q, const unsigned short* __restrict__ khi,
               const unsigned short* __restrict__ vt,
               unsigned short* __restrict__ oHi)
{
    __shared__ unsigned short Khi[64][104];
    __shared__ unsigned short Vt[80][72];

    const int tid = threadIdx.x;
    const int wq = tid >> 6;
    const int lane = tid & 63;
    const int lq = lane & 15;
    const int g = lane >> 4;
    const int h = blockIdx.y;
    const int qb = blockIdx.x * 128;

    const float* qh = q + (size_t)h * SEQ * HD;
    const unsigned short* khi_h = khi + (size_t)h * SEQ * HD;
    const unsigned short* vth = vt + (size_t)h * HD * SEQ;

    for (int i = tid; i < 64 * 24; i += 256) {
        const int r = i / 24, c = 80 + i % 24;
        Khi[r][c] = 0;
    }

    int kr_[5], kc_[5], vd_[5], vc_[5];
#pragma unroll
    for (int ii = 0; ii < 5; ++ii) {
        const int id = tid + 256 * ii;
        kr_[ii] = id / 20; kc_[ii] = (id % 20) * 4;
        vd_[ii] = id >> 4; vc_[ii] = (id & 15) * 4;
    }

    bf16x8 qhiF[2][3], qloF[2][3];
#pragma unroll
    for (int nf = 0; nf < 2; ++nf) {
        const int qr = qb + wq * 32 + nf * 16 + lq;
        const float* qp = qh + (size_t)qr * HD;
#pragma unroll
        for (int ks = 0; ks < 3; ++ks) {
            const int d0 = ks * 32 + g * 8;
            union { unsigned short u[8]; bf16x8 v; } uh, ul;
            if (d0 < 80) {
                float4 x0 = *(const float4*)(qp + d0);
                float4 x1 = *(const float4*)(qp + d0 + 4);
                float xs[8] = {x0.x, x0.y, x0.z, x0.w, x1.x, x1.y, x1.z, x1.w};
#pragma unroll
                for (int i = 0; i < 8; ++i) {
                    const unsigned short hb = f2bf(xs[i]);
                    uh.u[i] = hb;
                    ul.u[i] = f2bf(xs[i] - bf2f(hb));
                }
            } else {
#pragma unroll
                for (int i = 0; i < 8; ++i) { uh.u[i] = 0; ul.u[i] = 0; }
            }
            qhiF[nf][ks] = uh.v; qloF[nf][ks] = ul.v;
        }
    }

    f32x4 o[2][5];
#pragma unroll
    for (int a = 0; a < 2; ++a)
#pragma unroll
        for (int b = 0; b < 5; ++b) o[a][b] = (f32x4)0.f;
    float mrow[2] = {-1e30f, -1e30f};
    float lrow[2] = {0.f, 0.f};

    uint2 kh_[5], vv_[5];
#define LOADKV(kb_)                                                                   \
    do {                                                                              \
        _Pragma("unroll")                                                             \
        for (int ii = 0; ii < 5; ++ii) {                                              \
            kh_[ii] = *(const uint2*)&khi_h[(size_t)((kb_) + kr_[ii]) * HD + kc_[ii]];\
            vv_[ii] = *(const uint2*)&vth[(size_t)vd_[ii] * SEQ + (kb_) + vc_[ii]];   \
        }                                                                             \
    } while (0)

    LOADKV(0);

    for (int kb = 0; kb < SEQ; kb += 64) {
        __syncthreads();
#pragma unroll
        for (int ii = 0; ii < 5; ++ii) {
            *(uint2*)&Khi[kr_[ii]][kc_[ii]] = kh_[ii];
            *(uint2*)&Vt[vd_[ii]][vc_[ii]] = vv_[ii];
        }
        __syncthreads();
        if (kb + 64 < SEQ) LOADKV(kb + 64);

        f32x4 s[4][2];
#pragma unroll
        for (int mf = 0; mf < 4; ++mf)
#pragma unroll
            for (int nf = 0; nf < 2; ++nf) s[mf][nf] = (f32x4)0.f;
        __builtin_amdgcn_s_setprio(1);
#pragma unroll
        for (int ks = 0; ks < 3; ++ks) {
#pragma unroll
            for (int mf = 0; mf < 4; ++mf) {
                bf16x8 ah = *(const bf16x8*)&Khi[mf * 16 + lq][ks * 32 + g * 8];
#pragma unroll
                for (int nf = 0; nf < 2; ++nf) {
                    s[mf][nf] = MFMA16(ah, qhiF[nf][ks], s[mf][nf]);
                    s[mf][nf] = MFMA16(ah, qloF[nf][ks], s[mf][nf]);
                }
            }
        }
        __builtin_amdgcn_s_setprio(0);

        float alpha_s[2]; bool skip_s[2];
#pragma unroll
        for (int nf = 0; nf < 2; ++nf) {
            float mx = s[0][nf][0];
#pragma unroll
            for (int mf = 0; mf < 4; ++mf)
#pragma unroll
                for (int r = 0; r < 4; ++r) mx = fmaxf(mx, s[mf][nf][r]);
            mx = fmaxf(mx, __shfl_xor(mx, 16));
            mx = fmaxf(mx, __shfl_xor(mx, 32));
            const bool skip = __all(mx <= mrow[nf]);
            const float mnew = skip ? mrow[nf] : fmaxf(mrow[nf], mx);
            float sum = 0.f;
#pragma unroll
            for (int mf = 0; mf < 4; ++mf)
#pragma unroll
                for (int r = 0; r < 4; ++r) {
                    const float p = EXP2F(s[mf][nf][r] - mnew);
                    s[mf][nf][r] = p;
                    sum += p;
                }
            sum += __shfl_xor(sum, 16);
            sum += __shfl_xor(sum, 32);
            if (skip) {
                lrow[nf] += sum;
                alpha_s[nf] = 1.f;
            } else {
                const float a = EXP2F(mrow[nf] - mnew);
                lrow[nf] = lrow[nf] * a + sum;
                mrow[nf] = mnew;
                alpha_s[nf] = a;
            }
            skip_s[nf] = skip;
        }

#pragma unroll
        for (int qm = 0; qm < 2; ++qm) {
            if (!skip_s[qm]) {
#pragma unroll
                for (int r = 0; r < 4; ++r) {
                    const float ao = __shfl(alpha_s[qm], (g << 2) | r);
#pragma unroll
                    for (int dn = 0; dn < 5; ++dn) o[qm][dn][r] *= ao;
                }
            }
        }

        int pk[4][2][2];
#pragma unroll
        for (int mf = 0; mf < 4; ++mf)
#pragma unroll
            for (int nf = 0; nf < 2; ++nf) {
                pk[mf][nf][0] = packp(s[mf][nf][0], s[mf][nf][1]);
                pk[mf][nf][1] = packp(s[mf][nf][2], s[mf][nf][3]);
            }

        bf16x8 pfrag[2][2];
#pragma unroll
        for (int qm = 0; qm < 2; ++qm) {
#pragma unroll
            for (int ks2 = 0; ks2 < 2; ++ks2) {
                union { int w[4]; bf16x8 v; } pw;
#pragma unroll
                for (int j = 0; j < 4; ++j) {
                    const int srcLane = lq + 32 * ((lane >> 4) & 1) + 16 * (j >> 1);
                    const int vA = __shfl(pk[2 * ks2 + 0][qm][j & 1], srcLane);
                    const int vB = __shfl(pk[2 * ks2 + 1][qm][j & 1], srcLane);
                    pw.w[j] = (lane >> 5) ? vB : vA;
                }
                pfrag[qm][ks2] = pw.v;
            }
        }

        __builtin_amdgcn_s_setprio(1);
#pragma unroll
        for (int ks2 = 0; ks2 < 2; ++ks2) {
#pragma unroll
            for (int dn = 0; dn < 5; ++dn) {
                bf16x8 vb = *(const bf16x8*)&Vt[dn * 16 + lq][ks2 * 32 + g * 8];
#pragma unroll
                for (int qm = 0; qm < 2; ++qm)
                    o[qm][dn] = MFMA16(pfrag[qm][ks2], vb, o[qm][dn]);
            }
        }
        __builtin_amdgcn_s_setprio(0);
    }
#undef LOADKV

#pragma unroll
    for (int qm = 0; qm < 2; ++qm) {
        const float invl = 1.0f / lrow[qm];
#pragma unroll
        for (int r = 0; r < 4; ++r) {
            const float iv = __shfl(invl, (g << 2) | r);
            const int row = qb + wq * 32 + qm * 16 + g * 4 + r;
#pragma unroll
            for (int dn = 0; dn < 5; ++dn) {
                const float val = o[qm][dn][r] * iv;
                oHi[(size_t)row * DIM + h * HD + dn * 16 + lq] = f2bf(val);
            }
        }
    }
}

// ---------------------------------------------------------------------------
extern "C" void kernel_launch(void* const* d_in, const int* in_sizes, int n_in,
                              void* d_out, int out_size, void* d_ws, size_t ws_size,
                              hipStream_t stream)
{
    const float* hidden = (const float*)d_in[0];
    const float* cos_t  = (const float*)d_in[2];
    const float* sin_t  = (const float*)d_in[3];
    const float* qkv_w  = (const float*)d_in[4];
    const float* qkv_b  = (const float*)d_in[5];
    const float* proj_w = (const float*)d_in[6];
    const float* proj_b = (const float*)d_in[7];
    float* out = (float*)d_out;

    char* ws = (char*)d_ws;
    // R21-proven region map:
    float* qkv = (float*)ws;                                   // q fp32 [0, 21.0M)
    float* qf  = qkv;
    float* kf  = qkv + (size_t)NH * SEQ * HD;                  // k fp32 [21.0M, 41.9M)
    float* vf  = qkv + (size_t)2 * NH * SEQ * HD;              // v fp32 [41.9M, 62.9M)
    unsigned short* aHi = (unsigned short*)(ws + 20971520);    // over k fp32 (dead after rope)
    unsigned short* pHi = (unsigned short*)(ws + 41943040);    // over v fp32 (dead after vtrans)
    unsigned short* hHi = (unsigned short*)(ws + 62914560);    // hidden bf16 (dead after QKV gemm)
    unsigned short* khi = (unsigned short*)(ws + 62914560);    // over hHi (after QKV gemm)
    unsigned short* wHi = (unsigned short*)(ws + 73400320);    // qkv_w bf16 (dead after QKV gemm)
    unsigned short* vth = (unsigned short*)(ws + 73400320);    // over wHi (after QKV gemm)

    conv_kernel<<<2048, 256, 0, stream>>>(hidden, hHi, SEQ * DIM / 4);
    conv_kernel<<<2048, 256, 0, stream>>>(qkv_w, wHi, N3 * DIM / 4);

    gemm256<true><<<dim3(16 * (N3 / 256)), 512, 0, stream>>>(
        hHi, wHi, qkv_b, qkv);

    rope_split<<<(2 * NH * SEQ * 40 + 255) / 256, 256, 0, stream>>>(
        qf, kf, khi, cos_t, sin_t);

    vtrans_kernel<<<dim3(SEQ / 64, NH), 256, 0, stream>>>(vf, vth);

    conv_kernel<<<1024, 256, 0, stream>>>(proj_w, pHi, DIM * DIM / 4);

    attn_mfma<<<dim3(SEQ / 128, NH), 256, 0, stream>>>(qf, khi, vth, aHi);

    gemm_proj<<<dim3(DIM / 128, SEQ / 128), 256, 0, stream>>>(
        aHi, pHi, proj_b, out);
}